// Round 18
// baseline (278.833 us; speedup 1.0000x reference)
//
#include <hip/hip_runtime.h>

#define WW 12
#define CH 32    // CIN == CMID == COUT == 32
#define KERN 3
#define ROWB 384   // bytes per fp8 row = WW*CH; elements per bf16 row
#define EBLK 2048  // edges per sort block

typedef __attribute__((ext_vector_type(8))) short short8v;
typedef __attribute__((ext_vector_type(4))) short short4v;
typedef __attribute__((ext_vector_type(4))) float f32x4;

__device__ __forceinline__ unsigned short bf16rne(float v) {
  unsigned int u = __float_as_uint(v);
  return (unsigned short)((u + 0x7FFFu + ((u >> 16) & 1u)) >> 16);
}
__device__ __forceinline__ float bf16tof(unsigned int b) {
  return __uint_as_float(b << 16);
}

// exact-RNE f32 -> fp8 e4m3 (OCP, saturating, no NaN production)
__device__ __forceinline__ unsigned char fp8e4m3(float x) {
  unsigned int u = __float_as_uint(x);
  unsigned int s = (u >> 24) & 0x80u;
  float ax = fabsf(x);
  if (ax >= 464.f) return (unsigned char)(s | 0x7E);       // 448
  if (ax < 0.015625f) {                                    // subnormal: m = RNE(ax*512)
    int m = __float2int_rn(ax * 512.f);
    return (unsigned char)(s | (unsigned)m);               // m==8 carries to e=1,m=0
  }
  unsigned int au = u & 0x7fffffffu;
  au += 0x7FFFFu + ((au >> 20) & 1u);                      // RNE on 20 dropped bits
  int e = (int)(au >> 23) - 127 + 7;
  unsigned int m = (au >> 20) & 7u;
  if (e > 15 || (e == 15 && m == 7)) return (unsigned char)(s | 0x7E);
  return (unsigned char)(s | ((unsigned)e << 3) | m);
}

// decode 4 fp8 from one dword, fused multiply-accumulate into acc[0..3]
__device__ __forceinline__ void dec4fma(unsigned int u, float wh, float* acc) {
#if __has_builtin(__builtin_amdgcn_cvt_pk_f32_fp8)
  auto lo = __builtin_amdgcn_cvt_pk_f32_fp8((int)u, false);  // bytes 0,1
  auto hi = __builtin_amdgcn_cvt_pk_f32_fp8((int)u, true);   // bytes 2,3
  acc[0] = fmaf(wh, lo[0], acc[0]);
  acc[1] = fmaf(wh, lo[1], acc[1]);
  acc[2] = fmaf(wh, hi[0], acc[2]);
  acc[3] = fmaf(wh, hi[1], acc[3]);
#else
#pragma unroll
  for (int j = 0; j < 4; ++j) {
    unsigned int b = (u >> (8 * j)) & 0xffu;
    float f = __uint_as_float(((b & 0x80u) << 24) | ((b & 0x7fu) << 20)) * 0x1.0p120f;
    acc[j] = fmaf(wh, f, acc[j]);
  }
#endif
}

// ---------------------------------------------------------------------------
// K1: per-block coarse histogram of dst>>8 (LDS) + NON-RETURNING fixed-point
//     weighted-degree atomic: degq[dst] += round(Ew * 2^24).
__global__ __launch_bounds__(256) void histA_kernel(const int* __restrict__ dst,
                                                    const float* __restrict__ Ew,
                                                    unsigned int* __restrict__ degq,
                                                    int* __restrict__ blockhist,
                                                    int E, int NB) {
  __shared__ unsigned int hist[256];
  const int b = blockIdx.x;
  const int tid = threadIdx.x;
  hist[tid] = 0;
  __syncthreads();
  const int base = b * EBLK;
#pragma unroll
  for (int k = 0; k < EBLK / 256; ++k) {
    int e = base + k * 256 + tid;
    if (e < E) {
      int d = dst[e];
      atomicAdd(&hist[(unsigned)d >> 8], 1u);
      atomicAdd(&degq[d], (unsigned int)__float2int_rn(Ew[e] * 16777216.f));
    }
  }
  __syncthreads();
  blockhist[tid * NB + b] = (int)hist[tid];
}

// K1b: degq fixed-point -> dinv
__global__ void dinv_kernel(const unsigned int* __restrict__ degq,
                            float* __restrict__ dinv, int N) {
  int n = blockIdx.x * blockDim.x + threadIdx.x;
  if (n < N) {
    float deg = (float)degq[n] * (1.f / 16777216.f);
    dinv[n] = (deg > 0.f) ? rsqrtf(fmaxf(deg, 1e-12f)) : 0.f;
  }
}

// K2a/b/c: 3-kernel exclusive scan over M ints (scanB chunked: nb <= 256*chunk).
__global__ void scanA_kernel(const int* __restrict__ in, int* __restrict__ bsum, int M) {
  __shared__ int red[256];
  int i = blockIdx.x * 256 + threadIdx.x;
  red[threadIdx.x] = (i < M) ? in[i] : 0;
  __syncthreads();
  for (int o = 128; o > 0; o >>= 1) {
    if (threadIdx.x < o) red[threadIdx.x] += red[threadIdx.x + o];
    __syncthreads();
  }
  if (threadIdx.x == 0) bsum[blockIdx.x] = red[0];
}
__global__ void scanB_kernel(int* __restrict__ bsum, int nb) {
  __shared__ int tmp[256];
  int tid = threadIdx.x;
  int chunk = (nb + 255) / 256;
  int lo = tid * chunk, hi = min(lo + chunk, nb);
  int s = 0;
  for (int i = lo; i < hi; ++i) s += bsum[i];
  tmp[tid] = s;
  __syncthreads();
  for (int o = 1; o < 256; o <<= 1) {
    int t = (tid >= o) ? tmp[tid - o] : 0;
    __syncthreads();
    tmp[tid] += t;
    __syncthreads();
  }
  int run = tmp[tid] - s;   // exclusive prefix of this chunk
  for (int i = lo; i < hi; ++i) {
    int v = bsum[i];
    bsum[i] = run;
    run += v;
  }
}
__global__ void scanC_kernel(const int* __restrict__ in, const int* __restrict__ bsum,
                             int* __restrict__ out, int M) {
  __shared__ int tmp[256];
  int tid = threadIdx.x;
  int i = blockIdx.x * 256 + tid;
  int v = (i < M) ? in[i] : 0;
  tmp[tid] = v;
  __syncthreads();
  for (int o = 1; o < 256; o <<= 1) {
    int t = (tid >= o) ? tmp[tid - o] : 0;
    __syncthreads();
    tmp[tid] += t;
    __syncthreads();
  }
  if (i < M) out[i] = bsum[blockIdx.x] + tmp[tid] - v;
}

// K3 (FUSED coarse-scatter + pack; scatter blocks FRONT-LOADED at [0,NB)):
//  scatter blocks: LDS pos[] (hoisted scanout column); returning LDS atomic
//    yields the FINAL position. No global atomics.
//  pack blocks: 8 elems/thread; xt = bf16(x); xq = fp8(x * dinv[n])  <-- folds
//    the src-side norm factor into the gather operand. Tail pids pack weights.
__global__ __launch_bounds__(256) void scatpack_kernel(
    const int* __restrict__ src, const int* __restrict__ dst, const float* __restrict__ Ew,
    const int* __restrict__ scanout, unsigned long long* __restrict__ rec8,
    const float* __restrict__ x, const float* __restrict__ dinv,
    const float* __restrict__ Wcheb, const float* __restrict__ Wconv,
    unsigned short* __restrict__ xt, unsigned char* __restrict__ xq,
    unsigned short* __restrict__ wb01, unsigned short* __restrict__ wbc,
    int E, int N, int NB, int npackTot, int npx) {
  if ((int)blockIdx.x < NB) {
    const int b = blockIdx.x;
    __shared__ int pos[256];
    const int tid = threadIdx.x;
    pos[tid] = scanout[tid * NB + b];       // hoist: one column of scanout
    __syncthreads();
    int e = b * EBLK + tid;
    bool valid = e < E;
    int d = 0, s = 0;
    float w = 0.f;
    if (valid) { d = dst[e]; s = src[e]; w = Ew[e]; }
#pragma unroll
    for (int k = 0; k < EBLK / 256; ++k) {
      int e2 = e + 256;
      bool v2 = (k + 1 < EBLK / 256) && (e2 < E);
      int d2 = 0, s2 = 0;
      float w2 = 0.f;
      if (v2) { d2 = dst[e2]; s2 = src[e2]; w2 = Ew[e2]; }
      if (valid) {
        int bucket = (unsigned)d >> 8;
        int p = atomicAdd(&pos[bucket], 1);   // final position directly
        rec8[p] = ((unsigned long long)(unsigned)d << 32) |
                  ((unsigned)s << 16) | bf16rne(w);
      }
      e = e2; d = d2; s = s2; w = w2; valid = v2;
    }
    return;
  }
  int pid = blockIdx.x - NB;
  if (pid >= npackTot) return;
  if (pid < npx) {
    long long f = ((long long)pid * 256 + threadIdx.x) * 8;   // flat idx into x (w,n,c)
    const long long T = (long long)WW * N * CH;
    if (f >= T) return;
    float4 v0 = *(const float4*)(x + f);
    float4 v1 = *(const float4*)(x + f + 4);
    int w = (int)(f / ((long long)N * CH));
    int rem = (int)(f - (long long)w * N * CH);
    int n = rem >> 5;
    int c = rem & 31;                                   // multiple of 8
    const float dn = dinv[n];
    size_t o = (size_t)n * ROWB + w * CH + c;
    short4v h0, h1;
    h0[0] = (short)bf16rne(v0.x); h0[1] = (short)bf16rne(v0.y);
    h0[2] = (short)bf16rne(v0.z); h0[3] = (short)bf16rne(v0.w);
    h1[0] = (short)bf16rne(v1.x); h1[1] = (short)bf16rne(v1.y);
    h1[2] = (short)bf16rne(v1.z); h1[3] = (short)bf16rne(v1.w);
    *(short4v*)(xt + o) = h0;
    *(short4v*)(xt + o + 4) = h1;
    unsigned int q0 = (unsigned int)fp8e4m3(v0.x * dn) | ((unsigned int)fp8e4m3(v0.y * dn) << 8) |
                      ((unsigned int)fp8e4m3(v0.z * dn) << 16) | ((unsigned int)fp8e4m3(v0.w * dn) << 24);
    unsigned int q1 = (unsigned int)fp8e4m3(v1.x * dn) | ((unsigned int)fp8e4m3(v1.y * dn) << 8) |
                      ((unsigned int)fp8e4m3(v1.z * dn) << 16) | ((unsigned int)fp8e4m3(v1.w * dn) << 24);
    *(unsigned int*)(xq + o) = q0;
    *(unsigned int*)(xq + o + 4) = q1;
    return;
  }
  int id = (pid - npx) * 256 + threadIdx.x;
  if (id < 12 * 2 * 2 * 64 * 8) {
    int j = id & 7, l = (id >> 3) & 63, h = (id >> 9) & 1, m = (id >> 10) & 1, ww = id >> 11;
    int k = ((l >> 4) << 3) + j;
    int d = (l & 15) + (h << 4);
    wb01[id] = bf16rne(Wcheb[((size_t)(ww * 2 + m) * 32 + k) * 32 + d]);
  } else if (id < 24576 + 3 * 2 * 64 * 8) {
    int i2 = id - 24576;
    int j = i2 & 7, l = (i2 >> 3) & 63, h = (i2 >> 9) & 1, k = i2 >> 10;
    int c = ((l >> 4) << 3) + j;
    int o = (l & 15) + (h << 4);
    wbc[i2] = bf16rne(Wconv[((size_t)(o * 32 + c)) * 3 + k]);
  }
}

// K4: fine pass — one block per coarse bucket (256 nodes), prefetch-pipelined.
//     LDS histogram of dst&255 + LDS scan -> rowptr; LDS running-pos ranked
//     scatter -> final epair.  (dinv computed earlier; no qsum here.)
__global__ __launch_bounds__(256) void passB_kernel(
    const unsigned long long* __restrict__ rec8, const int* __restrict__ scanout,
    int* __restrict__ rowptr, unsigned int* __restrict__ epair, int N, int E, int NB) {
  __shared__ unsigned int hist[256];
  __shared__ int sub[256];
  __shared__ int tmp[256];
  const int B = blockIdx.x;
  const int tid = threadIdx.x;
  hist[tid] = 0;
  __syncthreads();
  const int bstart = scanout[B * NB];
  const int bend = scanout[(B + 1) * NB];
  // pass 1: count (prefetch-pipelined)
  {
    int i = bstart + tid;
    unsigned long long r = (i < bend) ? rec8[i] : 0;
    while (i < bend) {
      int i2 = i + 256;
      unsigned long long r2 = (i2 < bend) ? rec8[i2] : 0;
      atomicAdd(&hist[(int)((r >> 32) & 255u)], 1u);
      i = i2; r = r2;
    }
  }
  __syncthreads();
  int v = (int)hist[tid];
  tmp[tid] = v;
  __syncthreads();
  for (int o = 1; o < 256; o <<= 1) {
    int t = (tid >= o) ? tmp[tid - o] : 0;
    __syncthreads();
    tmp[tid] += t;
    __syncthreads();
  }
  sub[tid] = tmp[tid] - v;   // exclusive within bucket
  int n = (B << 8) + tid;
  if (n < N) rowptr[n] = bstart + sub[tid];
  if (B == 0 && tid == 0) rowptr[N] = E;
  __syncthreads();
  tmp[tid] = bstart + sub[tid];   // running position array
  __syncthreads();
  // pass 2: ranked scatter via running positions (2-link chain)
  {
    int i = bstart + tid;
    unsigned long long r = (i < bend) ? rec8[i] : 0;
    while (i < bend) {
      int i2 = i + 256;
      unsigned long long r2 = (i2 < bend) ? rec8[i2] : 0;
      int low = (int)((r >> 32) & 255u);
      int p = atomicAdd(&tmp[low], 1);
      epair[p] = (unsigned int)r;   // (src<<16)|bf16(Ew)
      i = i2; r = r2;
    }
  }
}

// K5: gather  zt[n,p](bf16) = -dinv[n] * sum_e Ew_e * xq'[src_e, p]
//     (dinv[src] pre-folded into xq'). One node per wave; lane l&31 owns
//     bytes [12l,12l+12); halves split edges; 8/4/1-deep unroll tiers.
__global__ __launch_bounds__(256) void gather_kernel(
    const int* __restrict__ rowptr, const unsigned int* __restrict__ epair,
    const float* __restrict__ dinv,
    const unsigned char* __restrict__ xq, unsigned short* __restrict__ zt, int N) {
  int gt = blockIdx.x * blockDim.x + threadIdx.x;
  int n = gt >> 6;
  if (n >= N) return;
  int lane = gt & 63;
  int half = lane >> 5;
  int l = lane & 31;

  float acc[WW];
#pragma unroll
  for (int j = 0; j < WW; ++j) acc[j] = 0.f;

  int i = rowptr[n] + half;
  const int i1 = rowptr[n + 1];
  // tier 1: 8 edges per half per iteration (24 row-loads in flight)
  for (; i + 14 < i1; i += 16) {
    unsigned int er[8];
#pragma unroll
    for (int u = 0; u < 8; ++u) er[u] = epair[i + 2 * u];
    unsigned int dw[8][3];
#pragma unroll
    for (int u = 0; u < 8; ++u) {
      const unsigned int* p = (const unsigned int*)(xq + (size_t)(er[u] >> 16) * ROWB + l * 12);
      dw[u][0] = p[0]; dw[u][1] = p[1]; dw[u][2] = p[2];
    }
#pragma unroll
    for (int u = 0; u < 8; ++u) {
      float w = bf16tof(er[u] & 0xffffu);
      dec4fma(dw[u][0], w, acc + 0);
      dec4fma(dw[u][1], w, acc + 4);
      dec4fma(dw[u][2], w, acc + 8);
    }
  }
  // tier 2: 4 edges per half
  for (; i + 6 < i1; i += 8) {
    unsigned int er[4];
#pragma unroll
    for (int u = 0; u < 4; ++u) er[u] = epair[i + 2 * u];
    unsigned int dw[4][3];
#pragma unroll
    for (int u = 0; u < 4; ++u) {
      const unsigned int* p = (const unsigned int*)(xq + (size_t)(er[u] >> 16) * ROWB + l * 12);
      dw[u][0] = p[0]; dw[u][1] = p[1]; dw[u][2] = p[2];
    }
#pragma unroll
    for (int u = 0; u < 4; ++u) {
      float w = bf16tof(er[u] & 0xffffu);
      dec4fma(dw[u][0], w, acc + 0);
      dec4fma(dw[u][1], w, acc + 4);
      dec4fma(dw[u][2], w, acc + 8);
    }
  }
  // tier 3: 1 edge per half
  for (; i < i1; i += 2) {
    unsigned int e0 = epair[i];
    const unsigned int* p0 = (const unsigned int*)(xq + (size_t)(e0 >> 16) * ROWB + l * 12);
    unsigned int a0 = p0[0], a1 = p0[1], a2 = p0[2];
    float w0 = bf16tof(e0 & 0xffffu);
    dec4fma(a0, w0, acc + 0); dec4fma(a1, w0, acc + 4); dec4fma(a2, w0, acc + 8);
  }
#pragma unroll
  for (int j = 0; j < WW; ++j) acc[j] += __shfl_xor(acc[j], 32);

  if (half == 0) {
    const float ndinv = -dinv[n];   // dst factor applied ONCE
    unsigned short* q = zt + (size_t)n * ROWB + l * 12;
    short4v o0, o1, o2;
#pragma unroll
    for (int j = 0; j < 4; ++j) {
      o0[j] = (short)bf16rne(acc[j] * ndinv);
      o1[j] = (short)bf16rne(acc[4 + j] * ndinv);
      o2[j] = (short)bf16rne(acc[8 + j] * ndinv);
    }
    *(short4v*)(q) = o0;
    *(short4v*)(q + 4) = o1;
    *(short4v*)(q + 8) = o2;
  }
}

// K6 (fused mix+conv, MFMA, rolling LDS ring): per wave, 16 nodes.
__global__ __launch_bounds__(256) void mc_kernel(
    const unsigned short* __restrict__ xt, const unsigned short* __restrict__ zt,
    const unsigned short* __restrict__ wb01, const unsigned short* __restrict__ wbc,
    const float* __restrict__ bcheb, const float* __restrict__ bconv,
    float* __restrict__ out, int N) {
  __shared__ __align__(16) unsigned short hts[4][4][16][40];  // [wave][ring][row][40-pad]
  const int wid = threadIdx.x >> 6;
  const int lane = threadIdx.x & 63;
  const int n0 = (blockIdx.x * 4 + wid) * 16;
  if (n0 >= N) return;
  const int kg = lane >> 4;
  const int arow = lane & 15;
  const int rrow = min(n0 + arow, N - 1);   // clamp tail reads

  short8v wcf0[3], wcf1[3];
#pragma unroll
  for (int k = 0; k < 3; ++k) {
    wcf0[k] = *(const short8v*)(wbc + (((k * 2 + 0) * 64 + lane) << 3));
    wcf1[k] = *(const short8v*)(wbc + (((k * 2 + 1) * 64 + lane) << 3));
  }
  const float bc0 = bconv[arow];
  const float bc1 = bconv[arow + 16];

  auto computeH = [&](int w) {
    const size_t fofs = (size_t)rrow * ROWB + w * CH + kg * 8;
    short8v xf = *(const short8v*)(xt + fofs);
    short8v zf = *(const short8v*)(zt + fofs);
    unsigned short* hrow = &hts[wid][w & 3][0][0];
#pragma unroll
    for (int h = 0; h < 2; ++h) {
      short8v w0f = *(const short8v*)(wb01 + ((((w * 2 + 0) * 2 + h) * 64 + lane) << 3));
      short8v w1f = *(const short8v*)(wb01 + ((((w * 2 + 1) * 2 + h) * 64 + lane) << 3));
      f32x4 acc = {0.f, 0.f, 0.f, 0.f};
      acc = __builtin_amdgcn_mfma_f32_16x16x32_bf16(xf, w0f, acc, 0, 0, 0);
      acc = __builtin_amdgcn_mfma_f32_16x16x32_bf16(zf, w1f, acc, 0, 0, 0);
      const int d = arow + (h << 4);
      const float bias = bcheb[w * CH + d];
#pragma unroll
      for (int r = 0; r < 4; ++r) {
        hrow[(kg * 4 + r) * 40 + d] = bf16rne(acc[r] + bias);
      }
    }
  };

  auto convT = [&](int t) {
    f32x4 a0 = {0.f, 0.f, 0.f, 0.f};
    f32x4 a1 = {0.f, 0.f, 0.f, 0.f};
#pragma unroll
    for (int k = 0; k < 3; ++k) {
      int w = t + k - 1;
      if (w < 0 || w >= WW) continue;
      short8v hf = *(const short8v*)(&hts[wid][w & 3][arow][kg * 8]);
      a0 = __builtin_amdgcn_mfma_f32_16x16x32_bf16(hf, wcf0[k], a0, 0, 0, 0);
      a1 = __builtin_amdgcn_mfma_f32_16x16x32_bf16(hf, wcf1[k], a1, 0, 0, 0);
    }
#pragma unroll
    for (int r = 0; r < 4; ++r) {
      int node = n0 + kg * 4 + r;
      if (node >= N) continue;               // guard tail writes
      float v0 = a0[r] + bc0;
      float v1 = a1[r] + bc1;
      v0 = (v0 >= 0.f) ? v0 : 0.01f * v0;
      v1 = (v1 >= 0.f) ? v1 : 0.01f * v1;
      size_t o = ((size_t)node * WW + t) * CH;
      out[o + arow] = v0;
      out[o + arow + 16] = v1;
    }
  };

  computeH(0);
  computeH(1);
  convT(0);
  for (int w = 2; w < WW; ++w) {
    computeH(w);
    convT(w - 1);
  }
  convT(WW - 1);
}

// ---------------------------------------------------------------------------
extern "C" void kernel_launch(void* const* d_in, const int* in_sizes, int n_in,
                              void* d_out, int out_size, void* d_ws, size_t ws_size,
                              hipStream_t stream) {
  const float* x     = (const float*)d_in[0];
  const int*   A     = (const int*)d_in[1];
  const float* Ew    = (const float*)d_in[2];
  const float* Wcheb = (const float*)d_in[3];
  const float* bcheb = (const float*)d_in[4];
  const float* Wconv = (const float*)d_in[5];
  const float* bconv = (const float*)d_in[6];
  float* out = (float*)d_out;

  const int E = in_sizes[2];
  const int N = in_sizes[0] / (WW * CH);
  const int* srcA = A;
  const int* dstA = A + E;

  char* ws = (char*)d_ws;
  size_t off = 0;
  auto alloc = [&](size_t bytes) -> void* {
    void* p = ws + off;
    off += (bytes + 255) / 256 * 256;
    return p;
  };
  const int NB = (E + EBLK - 1) / EBLK;        // sort blocks (782 for E=1.6M)
  const int M = 256 * NB;                      // coarse histogram table size
  const int NBUCK = (N + 255) / 256;           // coarse buckets (196)

  unsigned int* degq = (unsigned int*)alloc((size_t)N * 4);
  float* dinv    = (float*)alloc((size_t)N * 4);
  int* blockhist = (int*)alloc((size_t)M * 4);
  int* scanout   = (int*)alloc((size_t)(M + 1) * 4);
  int* bsum      = (int*)alloc((size_t)((M + 255) / 256) * 4);
  int* rowptr    = (int*)alloc((size_t)(N + 1) * 4);
  unsigned long long* rec8 = (unsigned long long*)alloc((size_t)E * 8);
  unsigned int* epair = (unsigned int*)alloc((size_t)E * 4);
  unsigned short* xt   = (unsigned short*)alloc((size_t)N * ROWB * 2);
  unsigned char*  xq   = (unsigned char*)alloc((size_t)N * ROWB);
  unsigned short* zt   = (unsigned short*)alloc((size_t)N * ROWB * 2);
  unsigned short* wb01 = (unsigned short*)alloc((size_t)24576 * 2);
  unsigned short* wbc  = (unsigned short*)alloc((size_t)3072 * 2);
  (void)ws_size;

  hipMemsetAsync(degq, 0, (size_t)N * 4, stream);

  // 1. coarse histogram + non-returning weighted-degree atomics
  histA_kernel<<<NB, 256, 0, stream>>>(dstA, Ew, degq, blockhist, E, NB);
  dinv_kernel<<<(N + 255) / 256, 256, 0, stream>>>(degq, dinv, N);

  // 2. exclusive scan of blockhist (chunked middle level handles large M)
  const int nbs = (M + 255) / 256;
  scanA_kernel<<<nbs, 256, 0, stream>>>(blockhist, bsum, M);
  scanB_kernel<<<1, 256, 0, stream>>>(bsum, nbs);
  scanC_kernel<<<nbs, 256, 0, stream>>>(blockhist, bsum, scanout, M);

  // 3. coarse scatter (front-loaded, LDS-pos) + packing (xq pre-scaled by dinv)
  const long long T = (long long)WW * N * CH;
  const int npx = (int)((T + 2047) / 2048);
  const int nwb = (24576 + 3072 + 255) / 256;
  const int npackTot = npx + nwb;
  scatpack_kernel<<<NB + npackTot, 256, 0, stream>>>(
      srcA, dstA, Ew, scanout, rec8, x, dinv, Wcheb, Wconv, xt, xq, wb01, wbc,
      E, N, NB, npackTot, npx);

  // 4. fine pass: rowptr + final epair (LDS-ranked, prefetch-pipelined)
  passB_kernel<<<NBUCK, 256, 0, stream>>>(rec8, scanout, rowptr, epair, N, E, NB);

  // 5. gather
  long long gtot = (long long)N * 64;
  gather_kernel<<<(unsigned)((gtot + 255) / 256), 256, 0, stream>>>(rowptr, epair, dinv, xq, zt, N);

  // 6. fused mix+conv
  int ntiles = (N + 15) / 16;
  int mcblocks = (ntiles + 3) / 4;
  mc_kernel<<<mcblocks, 256, 0, stream>>>(xt, zt, wb01, wbc, bcheb, bconv, out, N);
}

// Round 19
// 208.003 us; speedup vs baseline: 1.3405x; 1.3405x over previous
//
#include <hip/hip_runtime.h>

#define WW 12
#define CH 32    // CIN == CMID == COUT == 32
#define KERN 3
#define ROWB 384   // bytes per fp8 row = WW*CH; elements per bf16 row
#define EBLK 2048  // edges per sort block

typedef __attribute__((ext_vector_type(8))) short short8v;
typedef __attribute__((ext_vector_type(4))) short short4v;
typedef __attribute__((ext_vector_type(4))) float f32x4;

__device__ __forceinline__ unsigned short bf16rne(float v) {
  unsigned int u = __float_as_uint(v);
  return (unsigned short)((u + 0x7FFFu + ((u >> 16) & 1u)) >> 16);
}
__device__ __forceinline__ float bf16tof(unsigned int b) {
  return __uint_as_float(b << 16);
}

// exact-RNE f32 -> fp8 e4m3 (OCP, saturating, no NaN production)
__device__ __forceinline__ unsigned char fp8e4m3(float x) {
  unsigned int u = __float_as_uint(x);
  unsigned int s = (u >> 24) & 0x80u;
  float ax = fabsf(x);
  if (ax >= 464.f) return (unsigned char)(s | 0x7E);       // 448
  if (ax < 0.015625f) {                                    // subnormal: m = RNE(ax*512)
    int m = __float2int_rn(ax * 512.f);
    return (unsigned char)(s | (unsigned)m);               // m==8 carries to e=1,m=0
  }
  unsigned int au = u & 0x7fffffffu;
  au += 0x7FFFFu + ((au >> 20) & 1u);                      // RNE on 20 dropped bits
  int e = (int)(au >> 23) - 127 + 7;
  unsigned int m = (au >> 20) & 7u;
  if (e > 15 || (e == 15 && m == 7)) return (unsigned char)(s | 0x7E);
  return (unsigned char)(s | ((unsigned)e << 3) | m);
}

// decode 4 fp8 from one dword, fused multiply-accumulate into acc[0..3]
__device__ __forceinline__ void dec4fma(unsigned int u, float wh, float* acc) {
#if __has_builtin(__builtin_amdgcn_cvt_pk_f32_fp8)
  auto lo = __builtin_amdgcn_cvt_pk_f32_fp8((int)u, false);  // bytes 0,1
  auto hi = __builtin_amdgcn_cvt_pk_f32_fp8((int)u, true);   // bytes 2,3
  acc[0] = fmaf(wh, lo[0], acc[0]);
  acc[1] = fmaf(wh, lo[1], acc[1]);
  acc[2] = fmaf(wh, hi[0], acc[2]);
  acc[3] = fmaf(wh, hi[1], acc[3]);
#else
#pragma unroll
  for (int j = 0; j < 4; ++j) {
    unsigned int b = (u >> (8 * j)) & 0xffu;
    float f = __uint_as_float(((b & 0x80u) << 24) | ((b & 0x7fu) << 20)) * 0x1.0p120f;
    acc[j] = fmaf(wh, f, acc[j]);
  }
#endif
}

// ---------------------------------------------------------------------------
// K1: per-block coarse histogram of dst>>8 (LDS, non-returning atomics only).
//     blockhist[bucket*NB + b] = count of bucket in block b's edge range.
__global__ __launch_bounds__(256) void histA_kernel(const int* __restrict__ dst,
                                                    int* __restrict__ blockhist,
                                                    int E, int NB) {
  __shared__ unsigned int hist[256];
  const int b = blockIdx.x;
  const int tid = threadIdx.x;
  hist[tid] = 0;
  __syncthreads();
  const int base = b * EBLK;
#pragma unroll
  for (int k = 0; k < EBLK / 256; ++k) {
    int e = base + k * 256 + tid;
    if (e < E) atomicAdd(&hist[(unsigned)dst[e] >> 8], 1u);
  }
  __syncthreads();
  blockhist[tid * NB + b] = (int)hist[tid];
}

// K2a/b/c: 3-kernel exclusive scan over M ints (scanB chunked: nb <= 256*chunk).
__global__ void scanA_kernel(const int* __restrict__ in, int* __restrict__ bsum, int M) {
  __shared__ int red[256];
  int i = blockIdx.x * 256 + threadIdx.x;
  red[threadIdx.x] = (i < M) ? in[i] : 0;
  __syncthreads();
  for (int o = 128; o > 0; o >>= 1) {
    if (threadIdx.x < o) red[threadIdx.x] += red[threadIdx.x + o];
    __syncthreads();
  }
  if (threadIdx.x == 0) bsum[blockIdx.x] = red[0];
}
__global__ void scanB_kernel(int* __restrict__ bsum, int nb) {
  __shared__ int tmp[256];
  int tid = threadIdx.x;
  int chunk = (nb + 255) / 256;
  int lo = tid * chunk, hi = min(lo + chunk, nb);
  int s = 0;
  for (int i = lo; i < hi; ++i) s += bsum[i];
  tmp[tid] = s;
  __syncthreads();
  for (int o = 1; o < 256; o <<= 1) {
    int t = (tid >= o) ? tmp[tid - o] : 0;
    __syncthreads();
    tmp[tid] += t;
    __syncthreads();
  }
  int run = tmp[tid] - s;   // exclusive prefix of this chunk
  for (int i = lo; i < hi; ++i) {
    int v = bsum[i];
    bsum[i] = run;
    run += v;
  }
}
__global__ void scanC_kernel(const int* __restrict__ in, const int* __restrict__ bsum,
                             int* __restrict__ out, int M) {
  __shared__ int tmp[256];
  int tid = threadIdx.x;
  int i = blockIdx.x * 256 + tid;
  int v = (i < M) ? in[i] : 0;
  tmp[tid] = v;
  __syncthreads();
  for (int o = 1; o < 256; o <<= 1) {
    int t = (tid >= o) ? tmp[tid - o] : 0;
    __syncthreads();
    tmp[tid] += t;
    __syncthreads();
  }
  if (i < M) out[i] = bsum[blockIdx.x] + tmp[tid] - v;
}

// K3 (FUSED coarse-scatter + pack; scatter blocks FRONT-LOADED at [0,NB)):
//  scatter blocks: scanout column hoisted to LDS pos[] once per block; the
//    returning LDS atomic yields the FINAL position (2-link chain). No global
//    atomics, no separate hist pass.
//  pack blocks: 8 elems/thread x->xt(bf16)+xq(fp8); tail pids pack weights.
__global__ __launch_bounds__(256) void scatpack_kernel(
    const int* __restrict__ src, const int* __restrict__ dst, const float* __restrict__ Ew,
    const int* __restrict__ scanout, unsigned long long* __restrict__ rec8,
    const float* __restrict__ x, const float* __restrict__ Wcheb,
    const float* __restrict__ Wconv,
    unsigned short* __restrict__ xt, unsigned char* __restrict__ xq,
    unsigned short* __restrict__ wb01, unsigned short* __restrict__ wbc,
    int E, int N, int NB, int npackTot, int npx) {
  if ((int)blockIdx.x < NB) {
    const int b = blockIdx.x;
    __shared__ int pos[256];
    const int tid = threadIdx.x;
    pos[tid] = scanout[tid * NB + b];       // hoist: one column of scanout
    __syncthreads();
    int e = b * EBLK + tid;
    bool valid = e < E;
    int d = 0, s = 0;
    float w = 0.f;
    if (valid) { d = dst[e]; s = src[e]; w = Ew[e]; }
#pragma unroll
    for (int k = 0; k < EBLK / 256; ++k) {
      // prefetch next iteration before the dependent chain
      int e2 = e + 256;
      bool v2 = (k + 1 < EBLK / 256) && (e2 < E);
      int d2 = 0, s2 = 0;
      float w2 = 0.f;
      if (v2) { d2 = dst[e2]; s2 = src[e2]; w2 = Ew[e2]; }
      if (valid) {
        int bucket = (unsigned)d >> 8;
        int p = atomicAdd(&pos[bucket], 1);   // final position directly
        rec8[p] = ((unsigned long long)(unsigned)d << 32) |
                  ((unsigned)s << 16) | bf16rne(w);
      }
      e = e2; d = d2; s = s2; w = w2; valid = v2;
    }
    return;
  }
  int pid = blockIdx.x - NB;
  if (pid >= npackTot) return;
  if (pid < npx) {
    long long f = ((long long)pid * 256 + threadIdx.x) * 8;   // flat idx into x (w,n,c)
    const long long T = (long long)WW * N * CH;
    if (f >= T) return;
    float4 v0 = *(const float4*)(x + f);
    float4 v1 = *(const float4*)(x + f + 4);
    int w = (int)(f / ((long long)N * CH));
    int rem = (int)(f - (long long)w * N * CH);
    int n = rem >> 5;
    int c = rem & 31;                                   // multiple of 8
    size_t o = (size_t)n * ROWB + w * CH + c;
    short4v h0, h1;
    h0[0] = (short)bf16rne(v0.x); h0[1] = (short)bf16rne(v0.y);
    h0[2] = (short)bf16rne(v0.z); h0[3] = (short)bf16rne(v0.w);
    h1[0] = (short)bf16rne(v1.x); h1[1] = (short)bf16rne(v1.y);
    h1[2] = (short)bf16rne(v1.z); h1[3] = (short)bf16rne(v1.w);
    *(short4v*)(xt + o) = h0;
    *(short4v*)(xt + o + 4) = h1;
    unsigned int q0 = (unsigned int)fp8e4m3(v0.x) | ((unsigned int)fp8e4m3(v0.y) << 8) |
                      ((unsigned int)fp8e4m3(v0.z) << 16) | ((unsigned int)fp8e4m3(v0.w) << 24);
    unsigned int q1 = (unsigned int)fp8e4m3(v1.x) | ((unsigned int)fp8e4m3(v1.y) << 8) |
                      ((unsigned int)fp8e4m3(v1.z) << 16) | ((unsigned int)fp8e4m3(v1.w) << 24);
    *(unsigned int*)(xq + o) = q0;
    *(unsigned int*)(xq + o + 4) = q1;
    return;
  }
  int id = (pid - npx) * 256 + threadIdx.x;
  if (id < 12 * 2 * 2 * 64 * 8) {
    int j = id & 7, l = (id >> 3) & 63, h = (id >> 9) & 1, m = (id >> 10) & 1, ww = id >> 11;
    int k = ((l >> 4) << 3) + j;
    int d = (l & 15) + (h << 4);
    wb01[id] = bf16rne(Wcheb[((size_t)(ww * 2 + m) * 32 + k) * 32 + d]);
  } else if (id < 24576 + 3 * 2 * 64 * 8) {
    int i2 = id - 24576;
    int j = i2 & 7, l = (i2 >> 3) & 63, h = (i2 >> 9) & 1, k = i2 >> 10;
    int c = ((l >> 4) << 3) + j;
    int o = (l & 15) + (h << 4);
    wbc[i2] = bf16rne(Wconv[((size_t)(o * 32 + c)) * 3 + k]);
  }
}

// K4: fine pass — one block per coarse bucket (256 nodes), prefetch-pipelined.
//     LDS histogram of dst&255 + LDS scan -> rowptr + dinv; LDS running-pos
//     ranked scatter -> final epair.
__global__ __launch_bounds__(256) void passB_kernel(
    const unsigned long long* __restrict__ rec8, const int* __restrict__ scanout,
    int* __restrict__ rowptr, float* __restrict__ dinv,
    unsigned int* __restrict__ epair, int N, int E, int NB) {
  __shared__ unsigned int hist[256];
  __shared__ unsigned int qsum[256];
  __shared__ int sub[256];
  __shared__ int tmp[256];
  const int B = blockIdx.x;
  const int tid = threadIdx.x;
  hist[tid] = 0;
  qsum[tid] = 0;
  __syncthreads();
  const int bstart = scanout[B * NB];
  const int bend = scanout[(B + 1) * NB];
  // pass 1: count + weighted degree (prefetch-pipelined)
  {
    int i = bstart + tid;
    unsigned long long r = (i < bend) ? rec8[i] : 0;
    while (i < bend) {
      int i2 = i + 256;
      unsigned long long r2 = (i2 < bend) ? rec8[i2] : 0;
      int low = (int)((r >> 32) & 255u);
      atomicAdd(&hist[low], 1u);
      unsigned int q = (unsigned int)__float2int_rn(bf16tof((unsigned int)r & 0xffffu) * 16777216.f);
      atomicAdd(&qsum[low], q);
      i = i2; r = r2;
    }
  }
  __syncthreads();
  int v = (int)hist[tid];
  tmp[tid] = v;
  __syncthreads();
  for (int o = 1; o < 256; o <<= 1) {
    int t = (tid >= o) ? tmp[tid - o] : 0;
    __syncthreads();
    tmp[tid] += t;
    __syncthreads();
  }
  sub[tid] = tmp[tid] - v;   // exclusive within bucket
  int n = (B << 8) + tid;
  if (n < N) {
    rowptr[n] = bstart + sub[tid];
    float deg = (float)qsum[tid] * (1.f / 16777216.f);
    dinv[n] = (deg > 0.f) ? rsqrtf(fmaxf(deg, 1e-12f)) : 0.f;
  }
  if (B == 0 && tid == 0) rowptr[N] = E;
  __syncthreads();
  tmp[tid] = bstart + sub[tid];   // running position array
  __syncthreads();
  // pass 2: ranked scatter via running positions (2-link chain)
  {
    int i = bstart + tid;
    unsigned long long r = (i < bend) ? rec8[i] : 0;
    while (i < bend) {
      int i2 = i + 256;
      unsigned long long r2 = (i2 < bend) ? rec8[i2] : 0;
      int low = (int)((r >> 32) & 255u);
      int p = atomicAdd(&tmp[low], 1);
      epair[p] = (unsigned int)r;   // (src<<16)|bf16(Ew)
      i = i2; r = r2;
    }
  }
}

// K5: gather  zt[n,p](bf16) = sum_{e: dst=n} (-dinv[src]*Ew*dinv[n]) * fp8(x)[src, p]
//     one node per wave; lane l&31 owns bytes [12l,12l+12) of the 384B row;
//     halves split the edge list; 4 edges per half in flight; shfl_xor(32) combine.
__global__ __launch_bounds__(256) void gather_kernel(
    const int* __restrict__ rowptr, const unsigned int* __restrict__ epair,
    const float* __restrict__ dinv,
    const unsigned char* __restrict__ xq, unsigned short* __restrict__ zt, int N) {
  int gt = blockIdx.x * blockDim.x + threadIdx.x;
  int n = gt >> 6;
  if (n >= N) return;
  int lane = gt & 63;
  int half = lane >> 5;
  int l = lane & 31;

  const float ndinv = -dinv[n];

  float acc[WW];
#pragma unroll
  for (int j = 0; j < WW; ++j) acc[j] = 0.f;

  int i = rowptr[n] + half;
  const int i1 = rowptr[n + 1];
  for (; i + 6 < i1; i += 8) {
    unsigned int e0 = epair[i];
    unsigned int e1 = epair[i + 2];
    unsigned int e2 = epair[i + 4];
    unsigned int e3 = epair[i + 6];
    const unsigned int* p0 = (const unsigned int*)(xq + (size_t)(e0 >> 16) * ROWB + l * 12);
    const unsigned int* p1 = (const unsigned int*)(xq + (size_t)(e1 >> 16) * ROWB + l * 12);
    const unsigned int* p2 = (const unsigned int*)(xq + (size_t)(e2 >> 16) * ROWB + l * 12);
    const unsigned int* p3 = (const unsigned int*)(xq + (size_t)(e3 >> 16) * ROWB + l * 12);
    unsigned int a0 = p0[0], a1 = p0[1], a2 = p0[2];
    unsigned int b0 = p1[0], b1 = p1[1], b2 = p1[2];
    unsigned int c0 = p2[0], c1 = p2[1], c2 = p2[2];
    unsigned int d0 = p3[0], d1 = p3[1], d2 = p3[2];
    float w0 = ndinv * bf16tof(e0 & 0xffffu) * dinv[e0 >> 16];
    float w1 = ndinv * bf16tof(e1 & 0xffffu) * dinv[e1 >> 16];
    float w2 = ndinv * bf16tof(e2 & 0xffffu) * dinv[e2 >> 16];
    float w3 = ndinv * bf16tof(e3 & 0xffffu) * dinv[e3 >> 16];
    dec4fma(a0, w0, acc + 0); dec4fma(a1, w0, acc + 4); dec4fma(a2, w0, acc + 8);
    dec4fma(b0, w1, acc + 0); dec4fma(b1, w1, acc + 4); dec4fma(b2, w1, acc + 8);
    dec4fma(c0, w2, acc + 0); dec4fma(c1, w2, acc + 4); dec4fma(c2, w2, acc + 8);
    dec4fma(d0, w3, acc + 0); dec4fma(d1, w3, acc + 4); dec4fma(d2, w3, acc + 8);
  }
  for (; i < i1; i += 2) {
    unsigned int e0 = epair[i];
    const unsigned int* p0 = (const unsigned int*)(xq + (size_t)(e0 >> 16) * ROWB + l * 12);
    unsigned int a0 = p0[0], a1 = p0[1], a2 = p0[2];
    float w0 = ndinv * bf16tof(e0 & 0xffffu) * dinv[e0 >> 16];
    dec4fma(a0, w0, acc + 0); dec4fma(a1, w0, acc + 4); dec4fma(a2, w0, acc + 8);
  }
#pragma unroll
  for (int j = 0; j < WW; ++j) acc[j] += __shfl_xor(acc[j], 32);

  if (half == 0) {
    unsigned short* q = zt + (size_t)n * ROWB + l * 12;
    short4v o0, o1, o2;
#pragma unroll
    for (int j = 0; j < 4; ++j) {
      o0[j] = (short)bf16rne(acc[j]);
      o1[j] = (short)bf16rne(acc[4 + j]);
      o2[j] = (short)bf16rne(acc[8 + j]);
    }
    *(short4v*)(q) = o0;
    *(short4v*)(q + 4) = o1;
    *(short4v*)(q + 8) = o2;
  }
}

// K6 (fused mix+conv, MFMA, rolling LDS ring): per wave, 16 nodes.
__global__ __launch_bounds__(256) void mc_kernel(
    const unsigned short* __restrict__ xt, const unsigned short* __restrict__ zt,
    const unsigned short* __restrict__ wb01, const unsigned short* __restrict__ wbc,
    const float* __restrict__ bcheb, const float* __restrict__ bconv,
    float* __restrict__ out, int N) {
  __shared__ __align__(16) unsigned short hts[4][4][16][40];  // [wave][ring][row][40-pad]
  const int wid = threadIdx.x >> 6;
  const int lane = threadIdx.x & 63;
  const int n0 = (blockIdx.x * 4 + wid) * 16;
  if (n0 >= N) return;
  const int kg = lane >> 4;
  const int arow = lane & 15;
  const int rrow = min(n0 + arow, N - 1);   // clamp tail reads

  short8v wcf0[3], wcf1[3];
#pragma unroll
  for (int k = 0; k < 3; ++k) {
    wcf0[k] = *(const short8v*)(wbc + (((k * 2 + 0) * 64 + lane) << 3));
    wcf1[k] = *(const short8v*)(wbc + (((k * 2 + 1) * 64 + lane) << 3));
  }
  const float bc0 = bconv[arow];
  const float bc1 = bconv[arow + 16];

  auto computeH = [&](int w) {
    const size_t fofs = (size_t)rrow * ROWB + w * CH + kg * 8;
    short8v xf = *(const short8v*)(xt + fofs);
    short8v zf = *(const short8v*)(zt + fofs);
    unsigned short* hrow = &hts[wid][w & 3][0][0];
#pragma unroll
    for (int h = 0; h < 2; ++h) {
      short8v w0f = *(const short8v*)(wb01 + ((((w * 2 + 0) * 2 + h) * 64 + lane) << 3));
      short8v w1f = *(const short8v*)(wb01 + ((((w * 2 + 1) * 2 + h) * 64 + lane) << 3));
      f32x4 acc = {0.f, 0.f, 0.f, 0.f};
      acc = __builtin_amdgcn_mfma_f32_16x16x32_bf16(xf, w0f, acc, 0, 0, 0);
      acc = __builtin_amdgcn_mfma_f32_16x16x32_bf16(zf, w1f, acc, 0, 0, 0);
      const int d = arow + (h << 4);
      const float bias = bcheb[w * CH + d];
#pragma unroll
      for (int r = 0; r < 4; ++r) {
        hrow[(kg * 4 + r) * 40 + d] = bf16rne(acc[r] + bias);
      }
    }
  };

  auto convT = [&](int t) {
    f32x4 a0 = {0.f, 0.f, 0.f, 0.f};
    f32x4 a1 = {0.f, 0.f, 0.f, 0.f};
#pragma unroll
    for (int k = 0; k < 3; ++k) {
      int w = t + k - 1;
      if (w < 0 || w >= WW) continue;
      short8v hf = *(const short8v*)(&hts[wid][w & 3][arow][kg * 8]);
      a0 = __builtin_amdgcn_mfma_f32_16x16x32_bf16(hf, wcf0[k], a0, 0, 0, 0);
      a1 = __builtin_amdgcn_mfma_f32_16x16x32_bf16(hf, wcf1[k], a1, 0, 0, 0);
    }
#pragma unroll
    for (int r = 0; r < 4; ++r) {
      int node = n0 + kg * 4 + r;
      if (node >= N) continue;               // guard tail writes
      float v0 = a0[r] + bc0;
      float v1 = a1[r] + bc1;
      v0 = (v0 >= 0.f) ? v0 : 0.01f * v0;
      v1 = (v1 >= 0.f) ? v1 : 0.01f * v1;
      size_t o = ((size_t)node * WW + t) * CH;
      out[o + arow] = v0;
      out[o + arow + 16] = v1;
    }
  };

  computeH(0);
  computeH(1);
  convT(0);
  for (int w = 2; w < WW; ++w) {
    computeH(w);
    convT(w - 1);
  }
  convT(WW - 1);
}

// ---------------------------------------------------------------------------
extern "C" void kernel_launch(void* const* d_in, const int* in_sizes, int n_in,
                              void* d_out, int out_size, void* d_ws, size_t ws_size,
                              hipStream_t stream) {
  const float* x     = (const float*)d_in[0];
  const int*   A     = (const int*)d_in[1];
  const float* Ew    = (const float*)d_in[2];
  const float* Wcheb = (const float*)d_in[3];
  const float* bcheb = (const float*)d_in[4];
  const float* Wconv = (const float*)d_in[5];
  const float* bconv = (const float*)d_in[6];
  float* out = (float*)d_out;

  const int E = in_sizes[2];
  const int N = in_sizes[0] / (WW * CH);
  const int* srcA = A;
  const int* dstA = A + E;

  char* ws = (char*)d_ws;
  size_t off = 0;
  auto alloc = [&](size_t bytes) -> void* {
    void* p = ws + off;
    off += (bytes + 255) / 256 * 256;
    return p;
  };
  const int NB = (E + EBLK - 1) / EBLK;        // sort blocks (782 for E=1.6M)
  const int M = 256 * NB;                      // coarse histogram table size
  const int NBUCK = (N + 255) / 256;           // coarse buckets (196)

  int* blockhist = (int*)alloc((size_t)M * 4);
  int* scanout   = (int*)alloc((size_t)(M + 1) * 4);
  int* bsum      = (int*)alloc((size_t)((M + 255) / 256) * 4);
  int* rowptr    = (int*)alloc((size_t)(N + 1) * 4);
  float* dinv    = (float*)alloc((size_t)N * 4);
  unsigned long long* rec8 = (unsigned long long*)alloc((size_t)E * 8);
  unsigned int* epair = (unsigned int*)alloc((size_t)E * 4);
  unsigned short* xt   = (unsigned short*)alloc((size_t)N * ROWB * 2);
  unsigned char*  xq   = (unsigned char*)alloc((size_t)N * ROWB);
  unsigned short* zt   = (unsigned short*)alloc((size_t)N * ROWB * 2);
  unsigned short* wb01 = (unsigned short*)alloc((size_t)24576 * 2);
  unsigned short* wbc  = (unsigned short*)alloc((size_t)3072 * 2);
  (void)ws_size;

  // 1. coarse histogram (no global atomics, no memset needed anywhere)
  histA_kernel<<<NB, 256, 0, stream>>>(dstA, blockhist, E, NB);

  // 2. exclusive scan of blockhist (chunked middle level handles large M)
  const int nbs = (M + 255) / 256;
  scanA_kernel<<<nbs, 256, 0, stream>>>(blockhist, bsum, M);
  scanB_kernel<<<1, 256, 0, stream>>>(bsum, nbs);
  scanC_kernel<<<nbs, 256, 0, stream>>>(blockhist, bsum, scanout, M);

  // 3. coarse scatter (front-loaded, LDS-pos, prefetch-pipelined) + packing
  const long long T = (long long)WW * N * CH;
  const int npx = (int)((T + 2047) / 2048);
  const int nwb = (24576 + 3072 + 255) / 256;
  const int npackTot = npx + nwb;
  scatpack_kernel<<<NB + npackTot, 256, 0, stream>>>(
      srcA, dstA, Ew, scanout, rec8, x, Wcheb, Wconv, xt, xq, wb01, wbc,
      E, N, NB, npackTot, npx);

  // 4. fine pass: rowptr + dinv + final epair (LDS-ranked, prefetch-pipelined)
  passB_kernel<<<NBUCK, 256, 0, stream>>>(rec8, scanout, rowptr, dinv, epair, N, E, NB);

  // 5. gather
  long long gtot = (long long)N * 64;
  gather_kernel<<<(unsigned)((gtot + 255) / 256), 256, 0, stream>>>(rowptr, epair, dinv, xq, zt, N);

  // 6. fused mix+conv
  int ntiles = (N + 15) / 16;
  int mcblocks = (ntiles + 3) / 4;
  mc_kernel<<<mcblocks, 256, 0, stream>>>(xt, zt, wb01, wbc, bcheb, bconv, out, N);
}